// Round 18
// baseline (94958.423 us; speedup 1.0000x reference)
//
#include <hip/hip_runtime.h>

// KANSpikingNeuron — exact-arithmetic, v7: LDS-pipe wave-pressure test.
// Proven chain (r11): 8 flat K-blocks of 512 ascending; serial FMA chain per
// block; fp32 ascending merges (= global fp32 RMW); separate bias add; relu /
// >0 threshold. Arithmetic bit-identical to r12/r14/r17.
// Model: LDS-operand-BW bound (0.375 B/FLOP demand vs 0.17-0.21 supply);
// r17 dbuf-null rules out barrier/latency. This round: 16 waves/CU (512-thr
// blocks, 2/CU) to test whether effective LDS BW scales with wave pressure.

constexpr int B_TOT = 8192, IN = 4096, HID = 4096, OUT = 4096;
constexpr int BM = 256, BN = 256, BK = 16;
constexpr int KBLK = 512;
constexpr int NT = KBLK / BK;   // 32 tiles per pass (even)

// MODE: 0 = store blk; 1 = store fadd(prev, blk); 2 = final: bias + epilogue
template <int MODE, bool RELU>
__global__ __launch_bounds__(512, 4)   // 4 waves/SIMD -> 2 blocks/CU, cap 128
void gemm_pass(const float* __restrict__ A, const float* __restrict__ W,
               const float* __restrict__ bias, const float* Cprev,
               float* Cout, int N, int K, int k0) {
#pragma clang fp contract(off)
  __shared__ float As[2][BK][BM];   // 2 x 16 KB
  __shared__ float Ws[2][BK * BN];  // 2 x 16 KB, chunk-interleaved

  const int tid = threadIdx.x;
  const int tc = tid & 15;          // 16 col-groups of 16 -> BN 256
  const int tr = tid >> 4;          // 32 row-groups of 8  -> BM 256
  const int bm = blockIdx.y * BM;
  const int bn = blockIdx.x * BN;

  const int srow = tid >> 1;            // A staging row 0..255
  const int kbA = (tid & 1) * 8;        // A staging k-base (8 floats)
  const int wrowS = tid >> 1;           // W staging col 0..255
  const int kbW = (tid & 1) * 8;        // W staging k-base (8 floats)
  // W col c -> word ((c>>2)&3)*64 + (c>>4)*4 + (c&3); float4 reads 2-way free
  const int cw = ((wrowS >> 2) & 3) * 64 + (wrowS >> 4) * 4 + (wrowS & 3);

  const float* arow = A + (size_t)(bm + srow) * K + (k0 + kbA);
  const float* wrow = W + (size_t)(bn + wrowS) * K + (k0 + kbW);

  float4 av[2], wv[2];                  // tile-in-flight registers (16 VGPR)
#define PREFETCH(t)                                                         \
  {                                                                         \
    _Pragma("unroll") for (int u = 0; u < 2; ++u)                           \
        av[u] = *reinterpret_cast<const float4*>(arow + (t)*BK + 4 * u);    \
    _Pragma("unroll") for (int u = 0; u < 2; ++u)                           \
        wv[u] = *reinterpret_cast<const float4*>(wrow + (t)*BK + 4 * u);    \
  }
#define STAGE_WRITE(B)                                                      \
  {                                                                         \
    _Pragma("unroll") for (int u = 0; u < 2; ++u) {                         \
      const float va[4] = {av[u].x, av[u].y, av[u].z, av[u].w};             \
      _Pragma("unroll") for (int e = 0; e < 4; ++e)                         \
          As[B][kbA + 4 * u + e][srow] = va[e];                             \
    }                                                                       \
    _Pragma("unroll") for (int u = 0; u < 2; ++u) {                         \
      const float vw[4] = {wv[u].x, wv[u].y, wv[u].z, wv[u].w};             \
      _Pragma("unroll") for (int e = 0; e < 4; ++e)                         \
          Ws[B][(kbW + 4 * u + e) * BN + cw] = vw[e];                       \
    }                                                                       \
  }
#define COMPUTE(B)                                                          \
  _Pragma("unroll 2") for (int kk = 0; kk < BK; ++kk) {                     \
    float a[8], w[16];                                                      \
    *reinterpret_cast<float4*>(&a[0]) =                                     \
        *reinterpret_cast<const float4*>(&As[B][kk][tr * 8]);               \
    *reinterpret_cast<float4*>(&a[4]) =                                     \
        *reinterpret_cast<const float4*>(&As[B][kk][tr * 8 + 4]);           \
    _Pragma("unroll") for (int q = 0; q < 4; ++q)                           \
        *reinterpret_cast<float4*>(&w[4 * q]) =                             \
            *reinterpret_cast<const float4*>(                               \
                &Ws[B][kk * BN + q * 64 + tc * 4]);                         \
    _Pragma("unroll") for (int i = 0; i < 8; ++i)                           \
        _Pragma("unroll") for (int j = 0; j < 16; ++j)                      \
            blk[i][j] = __fmaf_rn(a[i], w[j], blk[i][j]);                   \
  }

  float blk[8][16];
#pragma unroll
  for (int i = 0; i < 8; ++i)
#pragma unroll
    for (int j = 0; j < 16; ++j) blk[i][j] = 0.0f;

  // prologue: buf0 <- tile0; R <- tile1
  PREFETCH(0)
  STAGE_WRITE(0)
  PREFETCH(1)
  __syncthreads();

  // steady state, 2 tiles per iteration (static buffer indices)
  for (int t = 0; t < NT; t += 2) {
    COMPUTE(0)
    STAGE_WRITE(1)                 // R holds tile t+1
    if (t + 2 < NT) PREFETCH(t + 2)
    __syncthreads();
    COMPUTE(1)
    if (t + 2 < NT) {
      STAGE_WRITE(0)               // R holds tile t+2
      if (t + 3 < NT) PREFETCH(t + 3)
    }
    __syncthreads();
  }
#undef PREFETCH
#undef STAGE_WRITE
#undef COMPUTE

  // ---- epilogue ----
  float bs[16];
  if constexpr (MODE == 2) {
#pragma unroll
    for (int j = 0; j < 16; ++j) bs[j] = bias[bn + tc * 16 + j];
  }
#pragma unroll
  for (int i = 0; i < 8; ++i) {
    const size_t base = (size_t)(bm + tr * 8 + i) * N + bn + tc * 16;
    float4 cv[4];
    if constexpr (MODE >= 1) {
#pragma unroll
      for (int q = 0; q < 4; ++q)
        cv[q] = *reinterpret_cast<const float4*>(Cprev + base + 4 * q);
    }
    float o[16];
#pragma unroll
    for (int j = 0; j < 16; ++j) {
      float v = blk[i][j];
      if constexpr (MODE >= 1) {
        const float pj = (&cv[j >> 2].x)[j & 3];
        v = __fadd_rn(pj, v);               // ascending block merge
      }
      if constexpr (MODE == 2) {
        v = __fadd_rn(v, bs[j]);            // separate fp32 bias add
        o[j] = RELU ? (v > 0.0f ? v : 0.0f) : (v > 0.0f ? 1.0f : 0.0f);
      } else {
        o[j] = v;                           // fp32 partial, exact
      }
    }
#pragma unroll
    for (int q = 0; q < 4; ++q)
      *reinterpret_cast<float4*>(Cout + base + 4 * q) =
          make_float4(o[4 * q], o[4 * q + 1], o[4 * q + 2], o[4 * q + 3]);
  }
}

static void run_layer(const float* A, const float* W, const float* bias,
                      float* partial, float* dest, bool relu, int rows,
                      int N, int K, hipStream_t stream) {
  const dim3 blk(512);
  const dim3 g(N / BN, rows / BM);
  const int NP = K / KBLK;   // 8 passes
  for (int p = 0; p < NP; ++p) {
    const int k0 = p * KBLK;
    if (p == 0) {
      gemm_pass<0, false><<<g, blk, 0, stream>>>(A, W, bias, nullptr, partial,
                                                 N, K, k0);
    } else if (p < NP - 1) {
      gemm_pass<1, false><<<g, blk, 0, stream>>>(A, W, bias, partial, partial,
                                                 N, K, k0);
    } else if (relu) {
      gemm_pass<2, true><<<g, blk, 0, stream>>>(A, W, bias, partial, dest,
                                                N, K, k0);
    } else {
      gemm_pass<2, false><<<g, blk, 0, stream>>>(A, W, bias, partial, dest,
                                                 N, K, k0);
    }
  }
}

extern "C" void kernel_launch(void* const* d_in, const int* in_sizes, int n_in,
                              void* d_out, int out_size, void* d_ws, size_t ws_size,
                              hipStream_t stream) {
  const float* x  = (const float*)d_in[0];
  const float* W1 = (const float*)d_in[1];
  const float* b1 = (const float*)d_in[2];
  const float* W2 = (const float*)d_in[3];
  const float* b2 = (const float*)d_in[4];
  float* out = (float*)d_out;

  size_t rows = ws_size / ((size_t)2 * HID * sizeof(float));
  rows = (rows / BM) * BM;
  if (rows > (size_t)B_TOT) rows = B_TOT;
  if (rows < BM) rows = BM;

  float* h   = (float*)d_ws;                         // rows x HID
  float* y2p = h + (size_t)rows * HID;               // rows x OUT

  for (int m0 = 0; m0 < B_TOT; m0 += (int)rows) {
    const int mrows = (B_TOT - m0 < (int)rows) ? (B_TOT - m0) : (int)rows;
    run_layer(x + (size_t)m0 * IN, W1, b1, h, h, true, mrows, HID, IN, stream);
    run_layer(h, W2, b2, y2p, out + (size_t)m0 * OUT, false, mrows, OUT, HID,
              stream);
  }
}

// Round 20
// 8698.354 us; speedup vs baseline: 10.9168x; 10.9168x over previous
//
#include <hip/hip_runtime.h>

// KANSpikingNeuron — exact-arithmetic, v9: scalar-pipe A + bijective W layout.
// Proven chain (r11): per element, 8 flat K-blocks of 512 ascending; serial
// FMA chain per block; fp32 ascending merges; separate fp32 bias add; relu
// (fp32 h) / >0 threshold. Reproduced bit-exactly with tot/blk registers.
// v8 bug: chunk_base() swizzle was NON-BIJECTIVE (g=7/g=8 overlap) -> LDS
// corruption. v9 layout (per k-row of 512 words): col c=8l+j -> word
// l*4 + (j&3) + 256*(j>>2). Reads = 2x ds_read_b128 at lane*4 / 256+lane*4
// (each instr covers every bank exactly 8x = conflict-free floor); writes
// 2-way per bank = free. Bijective by construction.
// Structure: 512 thr = 8 waves; wave owns 8 uniform rows (A via s_load, zero
// LDS); lane owns 8 cols (W via LDS, 32B/kk). BK=16 dbuf, 64KB LDS, (512,1).

constexpr int B_TOT = 8192, IN = 4096, HID = 4096, OUT = 4096;
constexpr int BM = 64, BN = 512, BK = 16;
constexpr int WSTR = 512;              // words per k-row
constexpr int KBLK_TILES = 512 / BK;   // 32 tiles per 512-k block

template <bool RELU>
__global__ __launch_bounds__(512, 1)
void gemm_sgpr(const float* __restrict__ A, const float* __restrict__ W,
               const float* __restrict__ bias, float* __restrict__ C,
               int N, int K) {
#pragma clang fp contract(off)
  __shared__ float Ws[2][BK * WSTR];   // 2 x 32 KB

  const int tid = threadIdx.x;
  const int lane = tid & 63;
  // wave index, forced wave-uniform -> A addressing stays in SGPRs (s_load)
  const int wv = __builtin_amdgcn_readfirstlane(tid >> 6);
  const int bm = blockIdx.y * BM;
  const int bn = blockIdx.x * BN;

  // A row pointers (wave-uniform)
  const float* Ar[8];
#pragma unroll
  for (int i = 0; i < 8; ++i)
    Ar[i] = A + (size_t)(bm + wv * 8 + i) * K;

  // W staging: thread owns col tid; its word within a k-row (bijective):
  const int cw = (tid >> 3) * 4 + (tid & 3) + ((tid & 4) << 6);
  const float* wrow = W + (size_t)(bn + tid) * K;
  // W read bases for this lane (cols lane*8..lane*8+3 / +4..+7)
  const int rb0 = lane * 4;
  const int rb1 = 256 + lane * 4;

  float4 wv4[4];
#define PREFETCH(t)                                                         \
  {                                                                         \
    _Pragma("unroll") for (int u = 0; u < 4; ++u)                           \
        wv4[u] = *reinterpret_cast<const float4*>(wrow + (t)*BK + 4 * u);   \
  }
#define STAGE_WRITE(B)                                                      \
  {                                                                         \
    _Pragma("unroll") for (int u = 0; u < 4; ++u) {                         \
      const float vw[4] = {wv4[u].x, wv4[u].y, wv4[u].z, wv4[u].w};         \
      _Pragma("unroll") for (int e = 0; e < 4; ++e)                         \
          Ws[B][(4 * u + e) * WSTR + cw] = vw[e];                           \
    }                                                                       \
  }
#define COMPUTE(B, t)                                                       \
  _Pragma("unroll") for (int kk = 0; kk < BK; ++kk) {                       \
    const int kg = (t)*BK + kk;                                             \
    float a[8];                                                             \
    _Pragma("unroll") for (int i = 0; i < 8; ++i) a[i] = Ar[i][kg];         \
    float w[8];                                                             \
    *reinterpret_cast<float4*>(&w[0]) =                                     \
        *reinterpret_cast<const float4*>(&Ws[B][kk * WSTR + rb0]);          \
    *reinterpret_cast<float4*>(&w[4]) =                                     \
        *reinterpret_cast<const float4*>(&Ws[B][kk * WSTR + rb1]);          \
    _Pragma("unroll") for (int i = 0; i < 8; ++i)                           \
        _Pragma("unroll") for (int j = 0; j < 8; ++j)                       \
            blk[i][j] = __fmaf_rn(a[i], w[j], blk[i][j]);                   \
  }
#define FOLD()                                                              \
  {                                                                         \
    _Pragma("unroll") for (int i = 0; i < 8; ++i)                           \
        _Pragma("unroll") for (int j = 0; j < 8; ++j) {                     \
      tot[i][j] = __fadd_rn(tot[i][j], blk[i][j]);                          \
      blk[i][j] = 0.0f;                                                     \
    }                                                                       \
  }

  float tot[8][8], blk[8][8];
#pragma unroll
  for (int i = 0; i < 8; ++i)
#pragma unroll
    for (int j = 0; j < 8; ++j) { tot[i][j] = 0.0f; blk[i][j] = 0.0f; }

  const int NT = K / BK;               // 256 tiles, ascending k

  // prologue: buf0 <- tile0; R <- tile1
  PREFETCH(0)
  STAGE_WRITE(0)
  PREFETCH(1)
  __syncthreads();

  for (int t = 0; t < NT; t += 2) {
    // 512-k block boundary (even t, multiple of 32): fold chain into total
    if (t > 0 && (t % KBLK_TILES) == 0) FOLD()
    COMPUTE(0, t)
    STAGE_WRITE(1)                 // R holds tile t+1
    if (t + 2 < NT) PREFETCH(t + 2)
    __syncthreads();
    // t+1 is never a 512-boundary (odd tile index)
    COMPUTE(1, t + 1)
    if (t + 2 < NT) {
      STAGE_WRITE(0)               // R holds tile t+2
      if (t + 3 < NT) PREFETCH(t + 3)
    }
    __syncthreads();
  }
#undef PREFETCH
#undef STAGE_WRITE
#undef COMPUTE
#undef FOLD

  // ---- epilogue: final fold + bias + relu/threshold, exact order ----
  float bs[8];
#pragma unroll
  for (int q = 0; q < 2; ++q)
    *reinterpret_cast<float4*>(&bs[4 * q]) =
        *reinterpret_cast<const float4*>(&bias[bn + lane * 8 + 4 * q]);
#pragma unroll
  for (int i = 0; i < 8; ++i) {
    const size_t base = (size_t)(bm + wv * 8 + i) * N + bn + lane * 8;
    float o[8];
#pragma unroll
    for (int j = 0; j < 8; ++j) {
      float v = __fadd_rn(tot[i][j], blk[i][j]);   // last 512-block fold
      v = __fadd_rn(v, bs[j]);                     // separate bias add
      if constexpr (RELU)
        o[j] = v > 0.0f ? v : 0.0f;
      else
        o[j] = v > 0.0f ? 1.0f : 0.0f;
    }
    *reinterpret_cast<float4*>(C + base) = make_float4(o[0], o[1], o[2], o[3]);
    *reinterpret_cast<float4*>(C + base + 4) =
        make_float4(o[4], o[5], o[6], o[7]);
  }
}

extern "C" void kernel_launch(void* const* d_in, const int* in_sizes, int n_in,
                              void* d_out, int out_size, void* d_ws, size_t ws_size,
                              hipStream_t stream) {
  const float* x  = (const float*)d_in[0];
  const float* W1 = (const float*)d_in[1];
  const float* b1 = (const float*)d_in[2];
  const float* W2 = (const float*)d_in[3];
  const float* b2 = (const float*)d_in[4];
  float* out = (float*)d_out;

  const dim3 blk(512);

  size_t rows = ws_size / ((size_t)HID * sizeof(float));
  rows = (rows / BM) * BM;
  if (rows > (size_t)B_TOT) rows = B_TOT;
  if (rows < BM) rows = BM;  // ws known ~512MiB
  float* h = (float*)d_ws;

  for (int m0 = 0; m0 < B_TOT; m0 += (int)rows) {
    const int mrows = (B_TOT - m0 < (int)rows) ? (B_TOT - m0) : (int)rows;
    const dim3 g1(HID / BN, mrows / BM);
    const dim3 g2(OUT / BN, mrows / BM);
    gemm_sgpr<true><<<g1, blk, 0, stream>>>(
        x + (size_t)m0 * IN, W1, b1, h, HID, IN);
    gemm_sgpr<false><<<g2, blk, 0, stream>>>(
        h, W2, b2, out + (size_t)m0 * OUT, OUT, HID);
  }
}